// Round 6
// baseline (1237.285 us; speedup 1.0000x reference)
//
#include <hip/hip_runtime.h>
#include <stdint.h>

#define B 8
#define N 8192
#define NG 512
#define GS 32

typedef unsigned long long ull;
typedef float v2f __attribute__((ext_vector_type(2)));

__device__ __forceinline__ float sq3(float dx, float dy, float dz) {
#pragma clang fp contract(off)
  return dx * dx + dy * dy + dz * dz;
}

// ---------------- Kernel 1: SE(3) transform, AoS xyz -> SoA xs/ys/zs ------
__global__ void transform_k(const float* __restrict__ xyz,
                            const float* __restrict__ pose,
                            float* __restrict__ xs, float* __restrict__ ys,
                            float* __restrict__ zs) {
#pragma clang fp contract(off)
  int i = blockIdx.x * blockDim.x + threadIdx.x;
  if (i >= B * N) return;
  int b = i / N;
  const float* P = pose + b * 12;  // (3,4) row-major: R|t
  float p0 = xyz[i * 3 + 0], p1 = xyz[i * 3 + 1], p2 = xyz[i * 3 + 2];
  float ox = ((P[0] * p0 + P[1] * p1) + P[2] * p2) + P[3];
  float oy = ((P[4] * p0 + P[5] * p1) + P[6] * p2) + P[7];
  float oz = ((P[8] * p0 + P[9] * p1) + P[10] * p2) + P[11];
  xs[i] = ox;
  ys[i] = oy;
  zs[i] = oz;
}

// ---------------- Kernel 2: farthest point sampling, 1 block per batch ----
// 256 threads (4 waves, 1 per SIMD), 32 points (16 float2) per thread.
// waves_per_eu(1,1): 512-VGPR budget -> px/py/pz/dist (~128 regs) resident.
// (R3 failed at this shape ONLY because default budget=92 forced per-step
// reloads; R4 proved residency works when arrays fit the budget.)
// ONE barrier per step; winner coords ride with per-wave partials; scan
// reads keys only (4x b64 broadcast) + 3x b32 coords of winning wave.
#define FPS_T 256
#define FPS_W (FPS_T / 64)     // 4 waves
#define FPS_J (N / FPS_T / 2)  // 16 float2 per thread

__global__ __launch_bounds__(FPS_T)
__attribute__((amdgpu_waves_per_eu(1, 1)))
void fps_k(const float* __restrict__ xs, const float* __restrict__ ys,
           const float* __restrict__ zs, float* __restrict__ centers) {
#pragma clang fp contract(off)
  int b = blockIdx.x;
  int t = threadIdx.x;
  __shared__ ull wkey[2][FPS_W];  // double-buffered per-wave winner key
  __shared__ float wx[2][FPS_W], wy[2][FPS_W], wz[2][FPS_W];  // winner coords
  __shared__ float cbuf[NG * 3];  // buffered centers (flush at end)

  const v2f* __restrict__ bx2 = (const v2f*)(xs + b * N);
  const v2f* __restrict__ by2 = (const v2f*)(ys + b * N);
  const v2f* __restrict__ bz2 = (const v2f*)(zs + b * N);

  // point (j, t, e) has global index p = (j*FPS_T + t)*2 + e
  v2f px[FPS_J], py[FPS_J], pz[FPS_J], dist[FPS_J];
#pragma unroll
  for (int j = 0; j < FPS_J; ++j) {
    int q = j * FPS_T + t;
    px[j] = bx2[q];
    py[j] = by2[q];
    pz[j] = bz2[q];
    dist[j].x = 1e10f;  // matches jnp.full(..., 1e10, f32)
    dist[j].y = 1e10f;
  }

  // publish point 0's coords (last = 0 at step 0) via LDS, once
  if (t == 0) {
    cbuf[0] = px[0].x;  // t==0 owns global point 0 (j=0, e=0)
    cbuf[1] = py[0].x;
    cbuf[2] = pz[0].x;
  }
  __syncthreads();
  float lx = cbuf[0], ly = cbuf[1], lz = cbuf[2];

  for (int k = 0; k < NG; ++k) {
    if (t == 0) {  // emit 'last' BEFORE update (scan output order)
      cbuf[k * 3 + 0] = lx;
      cbuf[k * 3 + 1] = ly;
      cbuf[k * 3 + 2] = lz;
    }

    // exact min-update + local max (packed f32 ops, IEEE-identical)
    float vmax = -1.0f;
#pragma unroll
    for (int j = 0; j < FPS_J; ++j) {
      v2f dx = px[j] - lx, dy = py[j] - ly, dz = pz[j] - lz;
      v2f d = (dx * dx + dy * dy) + dz * dz;
      v2f dm;
      dm.x = fminf(dist[j].x, d.x);
      dm.y = fminf(dist[j].y, d.y);
      dist[j] = dm;
      vmax = fmaxf(vmax, fmaxf(dm.x, dm.y));
    }
    // smallest local index achieving vmax (argmax-first semantics)
    int cand = 0x7fffffff;
#pragma unroll
    for (int j = 0; j < FPS_J; ++j) {
      int p = (j * FPS_T + t) * 2;
      cand = min(cand, (dist[j].x == vmax) ? p : 0x7fffffff);
      cand = min(cand, (dist[j].y == vmax) ? (p + 1) : 0x7fffffff);
    }
    // select coords of own candidate; independent of the butterfly below so
    // these cndmasks issue inside the ds latency shadows
    float cx = 0.f, cy = 0.f, cz = 0.f;
#pragma unroll
    for (int j = 0; j < FPS_J; ++j) {
      int p = (j * FPS_T + t) * 2;
      bool mx = (p == cand), my = (p + 1 == cand);
      cx = mx ? px[j].x : cx;
      cx = my ? px[j].y : cx;
      cy = mx ? py[j].x : cy;
      cy = my ? py[j].y : cy;
      cz = mx ? pz[j].x : cz;
      cz = my ? pz[j].y : cz;
    }

    // pack: max over key == max dist, tie -> min index (keys unique per lane)
    ull key0 = ((ull)__float_as_uint(vmax) << 32) | (ull)(unsigned)(N - 1 - cand);
    ull kr = key0;
#pragma unroll
    for (int off = 32; off >= 1; off >>= 1) {
      ull o = __shfl_xor(kr, off, 64);
      kr = (o > kr) ? o : kr;
    }
    // unique owner lane publishes key + coords for its wave
    int kb = k & 1;
    if (key0 == kr) {
      int w = t >> 6;
      wkey[kb][w] = kr;
      wx[kb][w] = cx;
      wy[kb][w] = cy;
      wz[kb][w] = cz;
    }
    __syncthreads();

    // cross-wave reduce over KEYS ONLY (4 b64 broadcast reads), then fetch
    // the winning wave's coords with 3 broadcast b32 reads
    ull gk = wkey[kb][0];
    int gw = 0;
#pragma unroll
    for (int w = 1; w < FPS_W; ++w) {
      ull o = wkey[kb][w];
      bool m = o > gk;
      gk = m ? o : gk;
      gw = m ? w : gw;
    }
    lx = wx[kb][gw];
    ly = wy[kb][gw];
    lz = wz[kb][gw];
    // no second barrier: buffer kb is only rewritten after barrier k+1, and
    // every reader of step k's partials reaches that barrier first
  }

  // flush centers (B, NG, 3)
  for (int i = t; i < NG * 3; i += FPS_T) centers[b * NG * 3 + i] = cbuf[i];
}

// ---------------- Kernel 3: exact 32-NN per center, 1 block per center ----
// Grouped cached-min rescan (4 groups of 8), ONE barrier per round.
// NO occupancy cap: knn is hidden by cross-block overlap (R4 lesson —
// waves_per_eu(2,2) cost ~65 us by cutting co-residency 5 -> 2 blocks/CU).
#define KNN_T 256
#define KNN_W (KNN_T / 64)  // 4 waves
#define KNN_P (N / KNN_T)   // 32 points per thread
#define KNN_G 4             // groups per thread
#define KNN_GS 8            // keys per group

__global__ __launch_bounds__(KNN_T) void knn_k(const float* __restrict__ xs,
                                               const float* __restrict__ ys,
                                               const float* __restrict__ zs,
                                               const float* __restrict__ centers,
                                               float* __restrict__ out) {
#pragma clang fp contract(off)
  int b = blockIdx.y, g = blockIdx.x, t = threadIdx.x;
  const float* bx = xs + b * N;
  const float* by = ys + b * N;
  const float* bz = zs + b * N;
  int ci = (b * NG + g) * 3;
  float cx = centers[ci], cy = centers[ci + 1], cz = centers[ci + 2];

  // packed keys: (distBits<<32)|idx ; min over key == min dist, tie -> min idx
  ull key[KNN_P];
  ull gmin[KNN_G];
#pragma unroll
  for (int gi = 0; gi < KNN_G; ++gi) {
    ull m = ~0ull;
#pragma unroll
    for (int jo = 0; jo < KNN_GS; ++jo) {
      int j = gi * KNN_GS + jo;
      int p = j * KNN_T + t;
      float dx = bx[p] - cx, dy = by[p] - cy, dz = bz[p] - cz;
      float d = sq3(dx, dy, dz);
      key[j] = ((ull)__float_as_uint(d) << 32) | (ull)(unsigned)p;
      m = (key[j] < m) ? key[j] : m;
    }
    gmin[gi] = m;
  }
  ull lmin = gmin[0];
#pragma unroll
  for (int gi = 1; gi < KNN_G; ++gi) lmin = (gmin[gi] < lmin) ? gmin[gi] : lmin;

  __shared__ ull wred[2][KNN_W];
  __shared__ int widx[GS];

  for (int k = 0; k < GS; ++k) {
    ull v = lmin;
#pragma unroll
    for (int off = 32; off >= 1; off >>= 1) {
      ull o = __shfl_xor(v, off, 64);
      v = (o < v) ? o : v;
    }
    int kb = k & 1;
    if ((t & 63) == 0) wred[kb][t >> 6] = v;
    __syncthreads();

    ull gm = wred[kb][0];
#pragma unroll
    for (int w = 1; w < KNN_W; ++w) {
      ull o = wred[kb][w];
      gm = (o < gm) ? o : gm;
    }
    int idx = (int)(unsigned)gm;

    // owner removes the extracted key; rescans ONLY its group of 8
    if (t == (idx & (KNN_T - 1))) {
      int gg = (idx >> 8) >> 3;  // j = idx>>8 ; group = j/8
#pragma unroll
      for (int gi = 0; gi < KNN_G; ++gi) {
        if (gg == gi) {
          ull m = ~0ull;
#pragma unroll
          for (int jo = 0; jo < KNN_GS; ++jo) {
            int j = gi * KNN_GS + jo;
            key[j] = (key[j] == gm) ? ~0ull : key[j];
            m = (key[j] < m) ? key[j] : m;
          }
          gmin[gi] = m;
        }
      }
      lmin = gmin[0];
#pragma unroll
      for (int gi = 1; gi < KNN_G; ++gi) lmin = (gmin[gi] < lmin) ? gmin[gi] : lmin;
    }
    if (t == 0) widx[k] = idx;
    // no second barrier: next round uses the other wred buffer;
    // widx[k] is only read after the final barrier below
  }
  __syncthreads();

  // gather & write neighborhood (B, NG, GS, 3), k ascending by (d, idx)
  if (t < GS) {
    int idx = widx[t];
    int o = ((b * NG + g) * GS + t) * 3;
    out[o + 0] = bx[idx];
    out[o + 1] = by[idx];
    out[o + 2] = bz[idx];
  }
}

extern "C" void kernel_launch(void* const* d_in, const int* in_sizes, int n_in,
                              void* d_out, int out_size, void* d_ws, size_t ws_size,
                              hipStream_t stream) {
  const float* xyz = (const float*)d_in[0];   // (B, N, 3) f32
  const float* pose = (const float*)d_in[1];  // (B, 3, 4) f32
  float* out = (float*)d_out;                 // neighborhood (B,NG,GS,3) ++ center (B,NG,3)

  float* xs = (float*)d_ws;  // SoA transformed points
  float* ys = xs + B * N;
  float* zs = ys + B * N;
  float* centers = out + B * NG * GS * 3;  // center block of d_out

  transform_k<<<dim3((B * N + 255) / 256), dim3(256), 0, stream>>>(xyz, pose, xs, ys, zs);
  fps_k<<<dim3(B), dim3(FPS_T), 0, stream>>>(xs, ys, zs, centers);
  knn_k<<<dim3(NG, B), dim3(KNN_T), 0, stream>>>(xs, ys, zs, centers, out);
}

// Round 7
// 1032.229 us; speedup vs baseline: 1.1987x; 1.1987x over previous
//
#include <hip/hip_runtime.h>
#include <stdint.h>

#define B 8
#define N 8192
#define NG 512
#define GS 32

typedef unsigned long long ull;
typedef float v2f __attribute__((ext_vector_type(2)));

__device__ __forceinline__ float sq3(float dx, float dy, float dz) {
#pragma clang fp contract(off)
  return dx * dx + dy * dy + dz * dz;
}

// ---------------- Kernel 1: SE(3) transform, AoS xyz -> SoA xs/ys/zs ------
__global__ void transform_k(const float* __restrict__ xyz,
                            const float* __restrict__ pose,
                            float* __restrict__ xs, float* __restrict__ ys,
                            float* __restrict__ zs) {
#pragma clang fp contract(off)
  int i = blockIdx.x * blockDim.x + threadIdx.x;
  if (i >= B * N) return;
  int b = i / N;
  const float* P = pose + b * 12;  // (3,4) row-major: R|t
  float p0 = xyz[i * 3 + 0], p1 = xyz[i * 3 + 1], p2 = xyz[i * 3 + 2];
  float ox = ((P[0] * p0 + P[1] * p1) + P[2] * p2) + P[3];
  float oy = ((P[4] * p0 + P[5] * p1) + P[6] * p2) + P[7];
  float oz = ((P[8] * p0 + P[9] * p1) + P[10] * p2) + P[11];
  xs[i] = ox;
  ys[i] = oy;
  zs[i] = oz;
}

// ---------------- Kernel 2: farthest point sampling, 1 block per batch ----
// R6 design, from the R0-R5 evidence:
//  * T=1024, 8 pts/thread (4 v2f): the ONLY shape where the compiler provably
//    keeps px/py/pz/dist in VGPRs (R0: VGPR=48). Larger per-thread arrays are
//    always rematerialized as per-step cache reloads (R1/R3/R4/R5).
//  * 4 waves/SIMD hide VALU/LDS latency; no waves_per_eu attribute (R5 lesson).
//  * ONE barrier per step (double-buffered partials), owner-publish coords,
//    keys-only scan; winning WAVE id is decoded from the key itself (no
//    cndmask gw-tracking chain - R4 lesson).
#define FPS_T 1024
#define FPS_W (FPS_T / 64)     // 16 waves
#define FPS_J (N / FPS_T / 2)  // 4 float2 per thread

__global__ __launch_bounds__(FPS_T) void fps_k(const float* __restrict__ xs,
                                               const float* __restrict__ ys,
                                               const float* __restrict__ zs,
                                               float* __restrict__ centers) {
#pragma clang fp contract(off)
  int b = blockIdx.x;
  int t = threadIdx.x;
  __shared__ ull wkey[2][FPS_W];  // double-buffered per-wave winner key
  __shared__ float wx[2][FPS_W], wy[2][FPS_W], wz[2][FPS_W];  // winner coords
  __shared__ float cbuf[NG * 3];  // buffered centers (flush at end)

  const v2f* __restrict__ bx2 = (const v2f*)(xs + b * N);
  const v2f* __restrict__ by2 = (const v2f*)(ys + b * N);
  const v2f* __restrict__ bz2 = (const v2f*)(zs + b * N);

  // point (j, t, e) has global index p = (j*FPS_T + t)*2 + e
  v2f px[FPS_J], py[FPS_J], pz[FPS_J], dist[FPS_J];
#pragma unroll
  for (int j = 0; j < FPS_J; ++j) {
    int q = j * FPS_T + t;
    px[j] = bx2[q];
    py[j] = by2[q];
    pz[j] = bz2[q];
    dist[j].x = 1e10f;  // matches jnp.full(..., 1e10, f32)
    dist[j].y = 1e10f;
  }

  // publish point 0's coords (last = 0 at step 0) via LDS, once
  if (t == 0) {
    cbuf[0] = px[0].x;  // t==0 owns global point 0 (j=0, e=0)
    cbuf[1] = py[0].x;
    cbuf[2] = pz[0].x;
  }
  __syncthreads();
  float lx = cbuf[0], ly = cbuf[1], lz = cbuf[2];

  for (int k = 0; k < NG; ++k) {
    if (t == 0) {  // emit 'last' BEFORE update (scan output order)
      cbuf[k * 3 + 0] = lx;
      cbuf[k * 3 + 1] = ly;
      cbuf[k * 3 + 2] = lz;
    }

    // exact min-update + local max (packed f32 ops, IEEE-identical)
    float vmax = -1.0f;
#pragma unroll
    for (int j = 0; j < FPS_J; ++j) {
      v2f dx = px[j] - lx, dy = py[j] - ly, dz = pz[j] - lz;
      v2f d = (dx * dx + dy * dy) + dz * dz;
      v2f dm;
      dm.x = fminf(dist[j].x, d.x);
      dm.y = fminf(dist[j].y, d.y);
      dist[j] = dm;
      vmax = fmaxf(vmax, fmaxf(dm.x, dm.y));
    }
    // smallest local index achieving vmax (argmax-first semantics)
    int cand = 0x7fffffff;
#pragma unroll
    for (int j = 0; j < FPS_J; ++j) {
      int p = (j * FPS_T + t) * 2;
      cand = min(cand, (dist[j].x == vmax) ? p : 0x7fffffff);
      cand = min(cand, (dist[j].y == vmax) ? (p + 1) : 0x7fffffff);
    }
    // select coords of own candidate (8 pts -> ~50 instrs, cheap at J=4);
    // independent of the butterfly so it hides under ds latency
    float cx = 0.f, cy = 0.f, cz = 0.f;
#pragma unroll
    for (int j = 0; j < FPS_J; ++j) {
      int p = (j * FPS_T + t) * 2;
      bool mx = (p == cand), my = (p + 1 == cand);
      cx = mx ? px[j].x : cx;
      cx = my ? px[j].y : cx;
      cy = mx ? py[j].x : cy;
      cy = my ? py[j].y : cy;
      cz = mx ? pz[j].x : cz;
      cz = my ? pz[j].y : cz;
    }

    // pack: max over key == max dist, tie -> min index (keys unique per lane)
    ull key0 = ((ull)__float_as_uint(vmax) << 32) | (ull)(unsigned)(N - 1 - cand);
    ull kr = key0;
#pragma unroll
    for (int off = 32; off >= 1; off >>= 1) {
      ull o = __shfl_xor(kr, off, 64);
      kr = (o > kr) ? o : kr;
    }
    // unique owner lane publishes key + coords for its wave
    int kb = k & 1;
    if (key0 == kr) {
      int w = t >> 6;
      wkey[kb][w] = kr;
      wx[kb][w] = cx;
      wy[kb][w] = cy;
      wz[kb][w] = cz;
    }
    __syncthreads();

    // cross-wave reduce over KEYS ONLY (16 b64 broadcast reads); the winning
    // wave id is DECODED FROM THE KEY (no select-tracking chain), then 3 b32
    // broadcast reads fetch that wave's coords
    ull gk = wkey[kb][0];
#pragma unroll
    for (int w = 1; w < FPS_W; ++w) {
      ull o = wkey[kb][w];
      gk = (o > gk) ? o : gk;
    }
    int wcand = N - 1 - (int)(unsigned)gk;        // winning point index
    int gw = ((wcand >> 1) & (FPS_T - 1)) >> 6;   // its thread's wave id
    lx = wx[kb][gw];
    ly = wy[kb][gw];
    lz = wz[kb][gw];
    // no second barrier: buffer kb is only rewritten after barrier k+1, and
    // every reader of step k's partials reaches that barrier first
  }

  // flush centers (B, NG, 3)
  for (int i = t; i < NG * 3; i += FPS_T) centers[b * NG * 3 + i] = cbuf[i];
}

// ---------------- Kernel 3: exact 32-NN per center, 1 block per center ----
// Grouped cached-min rescan (4 groups of 8), ONE barrier per round.
// NO occupancy cap (R4 lesson: capping cost ~65 us of cross-block overlap).
#define KNN_T 256
#define KNN_W (KNN_T / 64)  // 4 waves
#define KNN_P (N / KNN_T)   // 32 points per thread
#define KNN_G 4             // groups per thread
#define KNN_GS 8            // keys per group

__global__ __launch_bounds__(KNN_T) void knn_k(const float* __restrict__ xs,
                                               const float* __restrict__ ys,
                                               const float* __restrict__ zs,
                                               const float* __restrict__ centers,
                                               float* __restrict__ out) {
#pragma clang fp contract(off)
  int b = blockIdx.y, g = blockIdx.x, t = threadIdx.x;
  const float* bx = xs + b * N;
  const float* by = ys + b * N;
  const float* bz = zs + b * N;
  int ci = (b * NG + g) * 3;
  float cx = centers[ci], cy = centers[ci + 1], cz = centers[ci + 2];

  // packed keys: (distBits<<32)|idx ; min over key == min dist, tie -> min idx
  ull key[KNN_P];
  ull gmin[KNN_G];
#pragma unroll
  for (int gi = 0; gi < KNN_G; ++gi) {
    ull m = ~0ull;
#pragma unroll
    for (int jo = 0; jo < KNN_GS; ++jo) {
      int j = gi * KNN_GS + jo;
      int p = j * KNN_T + t;
      float dx = bx[p] - cx, dy = by[p] - cy, dz = bz[p] - cz;
      float d = sq3(dx, dy, dz);
      key[j] = ((ull)__float_as_uint(d) << 32) | (ull)(unsigned)p;
      m = (key[j] < m) ? key[j] : m;
    }
    gmin[gi] = m;
  }
  ull lmin = gmin[0];
#pragma unroll
  for (int gi = 1; gi < KNN_G; ++gi) lmin = (gmin[gi] < lmin) ? gmin[gi] : lmin;

  __shared__ ull wred[2][KNN_W];
  __shared__ int widx[GS];

  for (int k = 0; k < GS; ++k) {
    ull v = lmin;
#pragma unroll
    for (int off = 32; off >= 1; off >>= 1) {
      ull o = __shfl_xor(v, off, 64);
      v = (o < v) ? o : v;
    }
    int kb = k & 1;
    if ((t & 63) == 0) wred[kb][t >> 6] = v;
    __syncthreads();

    ull gm = wred[kb][0];
#pragma unroll
    for (int w = 1; w < KNN_W; ++w) {
      ull o = wred[kb][w];
      gm = (o < gm) ? o : gm;
    }
    int idx = (int)(unsigned)gm;

    // owner removes the extracted key; rescans ONLY its group of 8
    if (t == (idx & (KNN_T - 1))) {
      int gg = (idx >> 8) >> 3;  // j = idx>>8 ; group = j/8
#pragma unroll
      for (int gi = 0; gi < KNN_G; ++gi) {
        if (gg == gi) {
          ull m = ~0ull;
#pragma unroll
          for (int jo = 0; jo < KNN_GS; ++jo) {
            int j = gi * KNN_GS + jo;
            key[j] = (key[j] == gm) ? ~0ull : key[j];
            m = (key[j] < m) ? key[j] : m;
          }
          gmin[gi] = m;
        }
      }
      lmin = gmin[0];
#pragma unroll
      for (int gi = 1; gi < KNN_G; ++gi) lmin = (gmin[gi] < lmin) ? gmin[gi] : lmin;
    }
    if (t == 0) widx[k] = idx;
    // no second barrier: next round uses the other wred buffer;
    // widx[k] is only read after the final barrier below
  }
  __syncthreads();

  // gather & write neighborhood (B, NG, GS, 3), k ascending by (d, idx)
  if (t < GS) {
    int idx = widx[t];
    int o = ((b * NG + g) * GS + t) * 3;
    out[o + 0] = bx[idx];
    out[o + 1] = by[idx];
    out[o + 2] = bz[idx];
  }
}

extern "C" void kernel_launch(void* const* d_in, const int* in_sizes, int n_in,
                              void* d_out, int out_size, void* d_ws, size_t ws_size,
                              hipStream_t stream) {
  const float* xyz = (const float*)d_in[0];   // (B, N, 3) f32
  const float* pose = (const float*)d_in[1];  // (B, 3, 4) f32
  float* out = (float*)d_out;                 // neighborhood (B,NG,GS,3) ++ center (B,NG,3)

  float* xs = (float*)d_ws;  // SoA transformed points
  float* ys = xs + B * N;
  float* zs = ys + B * N;
  float* centers = out + B * NG * GS * 3;  // center block of d_out

  transform_k<<<dim3((B * N + 255) / 256), dim3(256), 0, stream>>>(xyz, pose, xs, ys, zs);
  fps_k<<<dim3(B), dim3(FPS_T), 0, stream>>>(xs, ys, zs, centers);
  knn_k<<<dim3(NG, B), dim3(KNN_T), 0, stream>>>(xs, ys, zs, centers, out);
}